// Round 3
// baseline (5775.747 us; speedup 1.0000x reference)
//
#include <hip/hip_runtime.h>
#include <hip/hip_cooperative_groups.h>
#include <math.h>

namespace cg = cooperative_groups;

#define BB 128
#define NN 256
#define HH 512
#define T_STEPS 32

__device__ __forceinline__ float fast_tanh(float x) {
    float e = __expf(2.0f * x);
    return 1.0f - 2.0f / (1.0f + e);
}
__device__ __forceinline__ float fast_sigmoid(float x) {
    return 1.0f / (1.0f + __expf(-x));
}

// C[i,k] = dot(enc[i,:], W1[k,:]) — 32768x512x512 fp32 GEMM, LDS-tiled,
// XOR-swizzled stores (write conflict-free, read 2-way=free).
#define SW(j, i) ((i) ^ ((((j) >> 2) & 7) << 2))
__global__ __launch_bounds__(256) void w1e_gemm(const float* __restrict__ enc,
                                                const float* __restrict__ W1,
                                                float* __restrict__ W1e) {
    __shared__ float As[32][64];
    __shared__ float Bs[32][64];
    int tid = threadIdx.x;
    int i0 = blockIdx.x * 64;
    int k0 = blockIdx.y * 64;
    int tx = tid & 15, ty = tid >> 4;
    int srow = tid >> 3, sq = tid & 7;

    float acc[4][4];
#pragma unroll
    for (int a = 0; a < 4; a++)
#pragma unroll
        for (int c = 0; c < 4; c++) acc[a][c] = 0.f;

    for (int j0 = 0; j0 < HH; j0 += 32) {
#pragma unroll
        for (int p = 0; p < 2; p++) {
            int row = p * 32 + srow;
            float4 av = *(const float4*)(enc + (size_t)(i0 + row) * HH + j0 + sq * 4);
            float4 bv = *(const float4*)(W1 + (size_t)(k0 + row) * HH + j0 + sq * 4);
#pragma unroll
            for (int c = 0; c < 4; c++) {
                int j = sq * 4 + c;
                float va = (c == 0) ? av.x : (c == 1) ? av.y : (c == 2) ? av.z : av.w;
                float vb = (c == 0) ? bv.x : (c == 1) ? bv.y : (c == 2) ? bv.z : bv.w;
                As[j][SW(j, row)] = va;
                Bs[j][SW(j, row)] = vb;
            }
        }
        __syncthreads();
#pragma unroll
        for (int j = 0; j < 32; j++) {
            float4 a = *(const float4*)&As[j][SW(j, tx * 4)];
            float4 b = *(const float4*)&Bs[j][SW(j, ty * 4)];
            float ar[4] = {a.x, a.y, a.z, a.w};
            float br[4] = {b.x, b.y, b.z, b.w};
#pragma unroll
            for (int ai = 0; ai < 4; ai++)
#pragma unroll
                for (int bk = 0; bk < 4; bk++)
                    acc[ai][bk] += ar[ai] * br[bk];
        }
        __syncthreads();
    }
#pragma unroll
    for (int ai = 0; ai < 4; ai++) {
        float4 r = make_float4(acc[ai][0], acc[ai][1], acc[ai][2], acc[ai][3]);
        *(float4*)(W1e + (size_t)(i0 + tx * 4 + ai) * HH + k0 + ty * 4) = r;
    }
}

// Cooperative kernel: all 32 decode steps. 256 blocks x 512 threads.
// Phase roles: GRU/W2H: block owns k0=blk*2 (weights LDS-resident across steps).
//              SCORE:   block (sb=blk>>1, hf=blk&1) owns n-half of batch row sb.
//              FINAL:   even block finalizes softmax/argmax/outputs/gather.
__global__ __launch_bounds__(512) void step_loop(
    const float* __restrict__ enc,
    const float* __restrict__ w_ih, const float* __restrict__ w_hh,
    const float* __restrict__ b_ih, const float* __restrict__ b_hh,
    const float* __restrict__ W2, const float* __restrict__ v,
    const float* __restrict__ W1e,
    float* __restrict__ hT0, float* __restrict__ hT1,
    float* __restrict__ xT, float* __restrict__ W2h,
    float* __restrict__ ubuf, float* __restrict__ lmax,
    int* __restrict__ lidx, int* __restrict__ mask,
    float* __restrict__ out) {
    cg::grid_group grid = cg::this_grid();
    __shared__ float wl[12 * HH];     // GRU weights for this block's 2 k (24KB)
    __shared__ float wl2[2 * HH];     // W2 rows (4KB)
    __shared__ float vl[HH];          // v (2KB)
    __shared__ float w2l[HH];         // per-step W2h row (2KB)
    __shared__ float scratch[3072];   // per-phase partials (12KB)
    __shared__ float sred[8];
    __shared__ int sredi[8];
    __shared__ float s_inv;

    int blk = blockIdx.x, tid = threadIdx.x;
    int k0 = blk * 2;

    // one-time weight staging
    for (int u = tid; u < 12 * HH; u += 512) {
        int r = u >> 9, j = u & (HH - 1);
        int s = r / 6, rem = r % 6;
        int m = rem / 3, g = rem % 3;
        int row = g * HH + k0 + s;
        const float* src = m ? w_hh : w_ih;
        wl[u] = src[(size_t)row * HH + j];
    }
    for (int u = tid; u < 2 * HH; u += 512)
        wl2[u] = W2[(size_t)(k0 + (u >> 9)) * HH + (u & (HH - 1))];
    vl[tid & (HH - 1)] = v[tid & (HH - 1)];
    // zero init of state
    int gid = blk * 512 + tid;
    if (gid < HH * BB) { hT0[gid] = 0.f; xT[gid] = 0.f; }
    if (gid < BB * NN) mask[gid] = 0;
    grid.sync();

    int b7 = tid & 127, grp = tid >> 7, s = grp & 1, jh = grp >> 1;
    int sb = blk >> 1, hf = blk & 1;

    for (int t = 0; t < T_STEPS; t++) {
        const float* hc = (t & 1) ? hT1 : hT0;
        float* hn = (t & 1) ? hT0 : hT1;

        // ---- GRU ----
        {
            const float* wp = wl + s * 6 * HH;
            float ai0 = 0.f, ai1 = 0.f, ai2 = 0.f, ah0 = 0.f, ah1 = 0.f, ah2 = 0.f;
            int jbeg = jh * 256, jend = jbeg + 256;
#pragma unroll 2
            for (int j = jbeg; j < jend; j += 4) {
                float4 wi0 = *(const float4*)(wp + j);
                float4 wi1 = *(const float4*)(wp + HH + j);
                float4 wi2 = *(const float4*)(wp + 2 * HH + j);
                float4 wh0 = *(const float4*)(wp + 3 * HH + j);
                float4 wh1 = *(const float4*)(wp + 4 * HH + j);
                float4 wh2 = *(const float4*)(wp + 5 * HH + j);
                float xv0 = xT[j * BB + b7], xv1 = xT[(j + 1) * BB + b7];
                float xv2 = xT[(j + 2) * BB + b7], xv3 = xT[(j + 3) * BB + b7];
                float hv0 = hc[j * BB + b7], hv1 = hc[(j + 1) * BB + b7];
                float hv2 = hc[(j + 2) * BB + b7], hv3 = hc[(j + 3) * BB + b7];
                ai0 += xv0 * wi0.x + xv1 * wi0.y + xv2 * wi0.z + xv3 * wi0.w;
                ai1 += xv0 * wi1.x + xv1 * wi1.y + xv2 * wi1.z + xv3 * wi1.w;
                ai2 += xv0 * wi2.x + xv1 * wi2.y + xv2 * wi2.z + xv3 * wi2.w;
                ah0 += hv0 * wh0.x + hv1 * wh0.y + hv2 * wh0.z + hv3 * wh0.w;
                ah1 += hv0 * wh1.x + hv1 * wh1.y + hv2 * wh1.z + hv3 * wh1.w;
                ah2 += hv0 * wh2.x + hv1 * wh2.y + hv2 * wh2.z + hv3 * wh2.w;
            }
            float* part = scratch + (grp * 128 + b7) * 6;
            part[0] = ai0; part[1] = ai1; part[2] = ai2;
            part[3] = ah0; part[4] = ah1; part[5] = ah2;
            __syncthreads();
            if (tid < 256) {
                int ss = tid >> 7, bb = tid & 127;
                const float* p0 = scratch + ((0 * 2 + ss) * 128 + bb) * 6;
                const float* p1 = scratch + ((1 * 2 + ss) * 128 + bb) * 6;
                int k = k0 + ss;
                float r = fast_sigmoid(p0[0] + p1[0] + b_ih[k] + p0[3] + p1[3] + b_hh[k]);
                float z = fast_sigmoid(p0[1] + p1[1] + b_ih[HH + k] + p0[4] + p1[4] + b_hh[HH + k]);
                float n = fast_tanh(p0[2] + p1[2] + b_ih[2 * HH + k] +
                                    r * (p0[5] + p1[5] + b_hh[2 * HH + k]));
                float hold = hc[k * BB + bb];
                hn[k * BB + bb] = (1.f - z) * n + z * hold;
            }
        }
        grid.sync();

        // ---- W2H ----
        {
            const float* wp = wl2 + s * HH;
            float acc = 0.f;
            int jbeg = jh * 256, jend = jbeg + 256;
#pragma unroll 4
            for (int j = jbeg; j < jend; j += 4) {
                float4 wv = *(const float4*)(wp + j);
                acc += hn[j * BB + b7] * wv.x + hn[(j + 1) * BB + b7] * wv.y +
                       hn[(j + 2) * BB + b7] * wv.z + hn[(j + 3) * BB + b7] * wv.w;
            }
            scratch[grp * 128 + b7] = acc;
            __syncthreads();
            if (tid < 256) {
                int ss = tid >> 7, bb = tid & 127;
                W2h[bb * HH + k0 + ss] = scratch[ss * 128 + bb] + scratch[(2 + ss) * 128 + bb];
            }
        }
        grid.sync();

        // ---- SCORE: u[sb, n] for this block's n-half ----
        {
            w2l[tid] = W2h[sb * HH + tid];
            __syncthreads();
            int nl = tid >> 2, q = tid & 3;
            int n = hf * 128 + nl;
            const float* Wp = W1e + ((size_t)sb * NN + n) * HH + q * 128;
            const float* w2p = w2l + q * 128;
            const float* vp = vl + q * 128;
            float part = 0.f;
#pragma unroll 4
            for (int jj = 0; jj < 128; jj += 4) {
                float4 wv = *(const float4*)(Wp + jj);
                float4 av = *(const float4*)(w2p + jj);
                float4 vv = *(const float4*)(vp + jj);
                part += fast_tanh(wv.x + av.x) * vv.x;
                part += fast_tanh(wv.y + av.y) * vv.y;
                part += fast_tanh(wv.z + av.z) * vv.z;
                part += fast_tanh(wv.w + av.w) * vv.w;
            }
            part += __shfl_xor(part, 1);
            part += __shfl_xor(part, 2);
            if (q == 0) scratch[nl] = part;
            __syncthreads();
            if (tid < 128) {
                int n2 = hf * 128 + tid;
                float val = mask[sb * NN + n2] ? -1.0e9f : scratch[tid];
                ubuf[sb * NN + n2] = val;
                float bv = val; int bi = n2;
                int lane = tid & 63;
                for (int off = 32; off > 0; off >>= 1) {
                    float ov = __shfl_down(bv, off);
                    int oi = __shfl_down(bi, off);
                    if (ov > bv || (ov == bv && oi < bi)) { bv = ov; bi = oi; }
                }
                if (lane == 0) { sred[tid >> 6] = bv; sredi[tid >> 6] = bi; }
            }
            __syncthreads();
            if (tid == 0) {
                float m = sred[0]; int mi = sredi[0];
                if (sred[1] > m || (sred[1] == m && sredi[1] < mi)) { m = sred[1]; mi = sredi[1]; }
                lmax[blk] = m; lidx[blk] = mi;
            }
        }
        grid.sync();

        // ---- FINAL (even block of each pair) ----
        if (hf == 0) {
            float m0 = lmax[blk], m1 = lmax[blk + 1];
            int i0 = lidx[blk], i1 = lidx[blk + 1];
            float m = m0; int idx = i0;
            if (m1 > m0) { m = m1; idx = i1; }  // tie -> lower half index (i0)
            float e = 0.f;
            if (tid < NN) e = expf(ubuf[sb * NN + tid] - m);
            float sv = e;
            int lane = tid & 63, wid = tid >> 6;
            for (int off = 32; off > 0; off >>= 1) sv += __shfl_down(sv, off);
            if (lane == 0) sred[wid] = sv;
            __syncthreads();
            if (tid == 0) s_inv = 1.0f / (sred[0] + sred[1] + sred[2] + sred[3]);
            __syncthreads();
            float inv = s_inv;
            float term = 0.f;
            if (tid < NN) {
                float p = e * inv;
                term = p * logf(p + 1e-9f);
            }
            float tv = term;
            for (int off = 32; off > 0; off >>= 1) tv += __shfl_down(tv, off);
            if (lane == 0) sred[wid] = tv;
            __syncthreads();
            if (tid == 0) {
                float ent = sred[0] + sred[1] + sred[2] + sred[3];
                out[sb * T_STEPS + t] = (float)idx;
                out[BB * T_STEPS + sb * T_STEPS + t] = logf(inv + 1e-9f);
                out[2 * BB * T_STEPS + sb * T_STEPS + t] = -ent;
                mask[sb * NN + idx] = 1;
            }
            // gather prev_embed for next step (idx uniform in registers)
            xT[tid * BB + sb] = enc[((size_t)sb * NN + idx) * HH + tid];
        }
        grid.sync();
    }
}

extern "C" void kernel_launch(void* const* d_in, const int* in_sizes, int n_in,
                              void* d_out, int out_size, void* d_ws, size_t ws_size,
                              hipStream_t stream) {
    const float* enc  = (const float*)d_in[0];
    const float* w_ih = (const float*)d_in[1];
    const float* w_hh = (const float*)d_in[2];
    const float* b_ih = (const float*)d_in[3];
    const float* b_hh = (const float*)d_in[4];
    const float* W1   = (const float*)d_in[5];
    const float* W2   = (const float*)d_in[6];
    const float* v    = (const float*)d_in[7];
    float* out = (float*)d_out;

    float* ws = (float*)d_ws;
    float* W1e = ws;                              // 16777216 floats (64 MB)
    float* hT0 = W1e + (size_t)BB * NN * HH;
    float* hT1 = hT0 + HH * BB;
    float* xT  = hT1 + HH * BB;
    float* W2h = xT + HH * BB;
    float* ubuf = W2h + HH * BB;                  // 32768
    float* lmax = ubuf + BB * NN;                 // 256
    int*   lidx = (int*)(lmax + 256);             // 256
    int*   mask = lidx + 256;                     // 32768

    w1e_gemm<<<dim3((BB * NN) / 64, HH / 64), 256, 0, stream>>>(enc, W1, W1e);

    void* args[] = {
        (void*)&enc, (void*)&w_ih, (void*)&w_hh, (void*)&b_ih, (void*)&b_hh,
        (void*)&W2, (void*)&v, (void*)&W1e, (void*)&hT0, (void*)&hT1,
        (void*)&xT, (void*)&W2h, (void*)&ubuf, (void*)&lmax, (void*)&lidx,
        (void*)&mask, (void*)&out};
    hipLaunchCooperativeKernel((void*)step_loop, dim3(256), dim3(512), args, 0, stream);
}

// Round 4
// 2780.483 us; speedup vs baseline: 2.0772x; 2.0772x over previous
//
#include <hip/hip_runtime.h>
#include <math.h>

#define BB 128
#define NN 256
#define HH 512
#define T_STEPS 32
#define JQ 128   // HH/4 j-quads

__device__ __forceinline__ float fast_tanh(float x) {
    float e = __expf(2.0f * x);
    return 1.0f - 2.0f / (1.0f + e);
}
__device__ __forceinline__ float fast_sigmoid(float x) {
    return 1.0f / (1.0f + __expf(-x));
}

// ---------------- W1e = enc @ W1^T  (32768x512x512 fp32, LDS-tiled, swizzled)
#define SW(j, i) ((i) ^ ((((j) >> 2) & 7) << 2))
__global__ __launch_bounds__(256) void w1e_gemm(const float* __restrict__ enc,
                                                const float* __restrict__ W1,
                                                float* __restrict__ W1e) {
    __shared__ float As[32][64];
    __shared__ float Bs[32][64];
    int tid = threadIdx.x;
    int i0 = blockIdx.x * 64;
    int k0 = blockIdx.y * 64;
    int tx = tid & 15, ty = tid >> 4;
    int srow = tid >> 3, sq = tid & 7;

    float acc[4][4];
#pragma unroll
    for (int a = 0; a < 4; a++)
#pragma unroll
        for (int c = 0; c < 4; c++) acc[a][c] = 0.f;

    for (int j0 = 0; j0 < HH; j0 += 32) {
#pragma unroll
        for (int p = 0; p < 2; p++) {
            int row = p * 32 + srow;
            float4 av = *(const float4*)(enc + (size_t)(i0 + row) * HH + j0 + sq * 4);
            float4 bv = *(const float4*)(W1 + (size_t)(k0 + row) * HH + j0 + sq * 4);
#pragma unroll
            for (int c = 0; c < 4; c++) {
                int j = sq * 4 + c;
                float va = (c == 0) ? av.x : (c == 1) ? av.y : (c == 2) ? av.z : av.w;
                float vb = (c == 0) ? bv.x : (c == 1) ? bv.y : (c == 2) ? bv.z : bv.w;
                As[j][SW(j, row)] = va;
                Bs[j][SW(j, row)] = vb;
            }
        }
        __syncthreads();
#pragma unroll
        for (int j = 0; j < 32; j++) {
            float4 a = *(const float4*)&As[j][SW(j, tx * 4)];
            float4 b = *(const float4*)&Bs[j][SW(j, ty * 4)];
            float ar[4] = {a.x, a.y, a.z, a.w};
            float br[4] = {b.x, b.y, b.z, b.w};
#pragma unroll
            for (int ai = 0; ai < 4; ai++)
#pragma unroll
                for (int bk = 0; bk < 4; bk++)
                    acc[ai][bk] += ar[ai] * br[bk];
        }
        __syncthreads();
    }
#pragma unroll
    for (int ai = 0; ai < 4; ai++) {
        float4 r = make_float4(acc[ai][0], acc[ai][1], acc[ai][2], acc[ai][3]);
        *(float4*)(W1e + (size_t)(i0 + tx * 4 + ai) * HH + k0 + ty * 4) = r;
    }
}

// ---------------- one-time weight transpose into lane-coalesced j-quad planes
// gT4[(g*JQ + jq)*HH + k] = float4{ w[(g%3)*HH + k][jq*4 .. +3] }, g<3: w_ih, else w_hh
// w2T4[jq*HH + k]         = float4{ W2[k][jq*4 .. +3] }
__global__ __launch_bounds__(512) void prep_kernel(const float* __restrict__ w_ih,
                                                   const float* __restrict__ w_hh,
                                                   const float* __restrict__ W2,
                                                   float4* __restrict__ gT4,
                                                   float4* __restrict__ w2T4) {
    int bid = blockIdx.x;
    int k = threadIdx.x;
    if (bid < 6 * JQ) {
        int g = bid / JQ, jq = bid % JQ;
        const float* src = (g < 3) ? w_ih : w_hh;
        const float* p = src + (size_t)((g % 3) * HH + k) * HH + jq * 4;
        gT4[(size_t)(g * JQ + jq) * HH + k] = make_float4(p[0], p[1], p[2], p[3]);
    } else {
        int jq = bid - 6 * JQ;
        const float* p = W2 + (size_t)k * HH + jq * 4;
        w2T4[(size_t)jq * HH + k] = make_float4(p[0], p[1], p[2], p[3]);
    }
}

// ---------------- persistent decoder: 1 block per batch row, all 32 steps local
__global__ __launch_bounds__(1024) void decode_kernel(
    const float* __restrict__ enc,
    const float* __restrict__ b_ih, const float* __restrict__ b_hh,
    const float4* __restrict__ gT4, const float4* __restrict__ w2T4,
    const float* __restrict__ v, const float* __restrict__ W1e,
    float* __restrict__ out) {
    __shared__ float x_l[HH];
    __shared__ float h_l[HH];
    __shared__ float vdup[4 * 132];    // padded q-duplicates (bank-conflict-free)
    __shared__ float w2dup[4 * 132];
    __shared__ float u_l[NN];
    __shared__ int mask_l[NN];
    __shared__ float part[12 * 512];   // [(gate*2+jh)*512 + k]
    __shared__ float wpart[2 * 512];
    __shared__ float redv[16];
    __shared__ int redi[16];
    __shared__ float s_m, s_inv;
    __shared__ int s_idx;

    int b = blockIdx.x, tid = threadIdx.x;
    int k = tid & 511, jh = tid >> 9;
    int jq0 = jh * 64;

    if (tid < HH) { x_l[tid] = 0.f; h_l[tid] = 0.f; }
    if (tid < 512) vdup[(tid >> 7) * 132 + (tid & 127)] = v[tid];
    if (tid < NN) mask_l[tid] = 0;
    __syncthreads();

    for (int t = 0; t < T_STEPS; t++) {
        // ---- GRU partials: thread (k, jh) does 6 dot-halves, coalesced weights
        {
            float a0 = 0.f, a1 = 0.f, a2 = 0.f, a3 = 0.f, a4 = 0.f, a5 = 0.f;
#pragma unroll 2
            for (int jq = jq0; jq < jq0 + 64; jq++) {
                float4 xq = *(const float4*)&x_l[jq * 4];
                float4 hq = *(const float4*)&h_l[jq * 4];
                float4 w0 = gT4[(size_t)(0 * JQ + jq) * HH + k];
                float4 w1 = gT4[(size_t)(1 * JQ + jq) * HH + k];
                float4 w2 = gT4[(size_t)(2 * JQ + jq) * HH + k];
                float4 w3 = gT4[(size_t)(3 * JQ + jq) * HH + k];
                float4 w4 = gT4[(size_t)(4 * JQ + jq) * HH + k];
                float4 w5 = gT4[(size_t)(5 * JQ + jq) * HH + k];
                a0 += xq.x * w0.x + xq.y * w0.y + xq.z * w0.z + xq.w * w0.w;
                a1 += xq.x * w1.x + xq.y * w1.y + xq.z * w1.z + xq.w * w1.w;
                a2 += xq.x * w2.x + xq.y * w2.y + xq.z * w2.z + xq.w * w2.w;
                a3 += hq.x * w3.x + hq.y * w3.y + hq.z * w3.z + hq.w * w3.w;
                a4 += hq.x * w4.x + hq.y * w4.y + hq.z * w4.z + hq.w * w4.w;
                a5 += hq.x * w5.x + hq.y * w5.y + hq.z * w5.z + hq.w * w5.w;
            }
            part[(0 * 2 + jh) * 512 + k] = a0;
            part[(1 * 2 + jh) * 512 + k] = a1;
            part[(2 * 2 + jh) * 512 + k] = a2;
            part[(3 * 2 + jh) * 512 + k] = a3;
            part[(4 * 2 + jh) * 512 + k] = a4;
            part[(5 * 2 + jh) * 512 + k] = a5;
        }
        __syncthreads();
        // ---- GRU combine + gates
        if (tid < HH) {
            int kk = tid;
            float ir = part[kk] + part[512 + kk];
            float iz = part[1024 + kk] + part[1536 + kk];
            float in = part[2048 + kk] + part[2560 + kk];
            float hr = part[3072 + kk] + part[3584 + kk];
            float hz = part[4096 + kk] + part[4608 + kk];
            float hn = part[5120 + kk] + part[5632 + kk];
            float r = fast_sigmoid(ir + b_ih[kk] + hr + b_hh[kk]);
            float z = fast_sigmoid(iz + b_ih[HH + kk] + hz + b_hh[HH + kk]);
            float n = fast_tanh(in + b_ih[2 * HH + kk] + r * (hn + b_hh[2 * HH + kk]));
            h_l[kk] = (1.f - z) * n + z * h_l[kk];
        }
        __syncthreads();

        // ---- W2h
        {
            float acc = 0.f;
#pragma unroll 4
            for (int jq = jq0; jq < jq0 + 64; jq++) {
                float4 hq = *(const float4*)&h_l[jq * 4];
                float4 w = w2T4[(size_t)jq * HH + k];
                acc += hq.x * w.x + hq.y * w.y + hq.z * w.z + hq.w * w.w;
            }
            wpart[jh * 512 + k] = acc;
        }
        __syncthreads();
        if (tid < 512)
            w2dup[(tid >> 7) * 132 + (tid & 127)] = wpart[tid] + wpart[512 + tid];
        __syncthreads();

        // ---- score u[n] = sum_k tanh(W1e + W2h) * v ; thread (n=tid>>2, q=tid&3)
        {
            int n = tid >> 2, q = tid & 3;
            const float* Wp = W1e + ((size_t)b * NN + n) * HH + q * 128;
            const float* w2p = w2dup + q * 132;
            const float* vp = vdup + q * 132;
            float p = 0.f;
#pragma unroll 8
            for (int jj = 0; jj < 128; jj += 4) {
                float4 wv = *(const float4*)(Wp + jj);
                float4 av = *(const float4*)(w2p + jj);
                float4 vv = *(const float4*)(vp + jj);
                p += fast_tanh(wv.x + av.x) * vv.x;
                p += fast_tanh(wv.y + av.y) * vv.y;
                p += fast_tanh(wv.z + av.z) * vv.z;
                p += fast_tanh(wv.w + av.w) * vv.w;
            }
            p += __shfl_xor(p, 1);
            p += __shfl_xor(p, 2);
            if (q == 0) u_l[n] = p;
        }
        __syncthreads();

        // ---- pass 1: masked first-max argmax (threads 0..255 = 4 full waves)
        float val = -3.0e38f;
        if (tid < NN) {
            val = mask_l[tid] ? -1.0e9f : u_l[tid];
            float bv = val;
            int bi = tid;
            int lane = tid & 63;
            for (int off = 32; off > 0; off >>= 1) {
                float ov = __shfl_down(bv, off);
                int oi = __shfl_down(bi, off);
                if (ov > bv || (ov == bv && oi < bi)) { bv = ov; bi = oi; }
            }
            if (lane == 0) { redv[tid >> 6] = bv; redi[tid >> 6] = bi; }
        }
        __syncthreads();
        if (tid == 0) {
            float m = redv[0]; int mi = redi[0];
            for (int w = 1; w < 4; w++)
                if (redv[w] > m || (redv[w] == m && redi[w] < mi)) { m = redv[w]; mi = redi[w]; }
            s_m = m; s_idx = mi;
        }
        __syncthreads();

        // ---- pass 2: softmax sum + entropy-sum in one reduction
        if (tid < NN) {
            float d = val - s_m;
            float e = expf(d);
            float ed = e * d;
            int lane = tid & 63;
            for (int off = 32; off > 0; off >>= 1) {
                e += __shfl_down(e, off);
                ed += __shfl_down(ed, off);
            }
            if (lane == 0) { redv[tid >> 6] = e; redv[8 + (tid >> 6)] = ed; }
        }
        __syncthreads();
        if (tid == 0) {
            float S = redv[0] + redv[1] + redv[2] + redv[3];
            float ED = redv[8] + redv[9] + redv[10] + redv[11];
            float inv = 1.0f / S;
            int idx = s_idx;
            out[b * T_STEPS + t] = (float)idx;
            out[BB * T_STEPS + b * T_STEPS + t] = logf(inv + 1e-9f);
            out[2 * BB * T_STEPS + b * T_STEPS + t] = logf(S) - inv * ED;
            mask_l[idx] = 1;
        }
        __syncthreads();
        // ---- gather prev_embed for next step
        if (tid < HH) x_l[tid] = enc[((size_t)b * NN + s_idx) * HH + tid];
        __syncthreads();
    }
}

extern "C" void kernel_launch(void* const* d_in, const int* in_sizes, int n_in,
                              void* d_out, int out_size, void* d_ws, size_t ws_size,
                              hipStream_t stream) {
    const float* enc  = (const float*)d_in[0];
    const float* w_ih = (const float*)d_in[1];
    const float* w_hh = (const float*)d_in[2];
    const float* b_ih = (const float*)d_in[3];
    const float* b_hh = (const float*)d_in[4];
    const float* W1   = (const float*)d_in[5];
    const float* W2   = (const float*)d_in[6];
    const float* v    = (const float*)d_in[7];
    float* out = (float*)d_out;

    float* ws = (float*)d_ws;
    float*  W1e  = ws;                                  // 16777216 floats (64 MB)
    float4* gT4  = (float4*)(W1e + (size_t)BB * NN * HH);  // 393216 float4 (6 MB)
    float4* w2T4 = gT4 + (size_t)6 * JQ * HH;              // 65536 float4 (1 MB)

    w1e_gemm<<<dim3((BB * NN) / 64, HH / 64), 256, 0, stream>>>(enc, W1, W1e);
    prep_kernel<<<7 * JQ, 512, 0, stream>>>(w_ih, w_hh, W2, gT4, w2T4);
    decode_kernel<<<BB, 1024, 0, stream>>>(enc, b_ih, b_hh, gT4, w2T4, v, W1e, out);
}